// Round 6
// baseline (1035.407 us; speedup 1.0000x reference)
//
#include <hip/hip_runtime.h>
#include <hip/hip_bf16.h>
#include <hip/hip_cooperative_groups.h>
#include <stdint.h>

namespace cg = cooperative_groups;

#define B_  16
#define N_  2048
#define D_  2
#define H_  128
#define CH_ 32
#define NEG_ (-1e9f)

typedef __attribute__((ext_vector_type(8))) short bf16x8;
typedef __attribute__((ext_vector_type(4))) float f32x4;
typedef __attribute__((ext_vector_type(4))) int   v4i;
typedef unsigned short u16;
typedef signed char    i8;

__device__ inline u16 f2bf(float f){
    union { __hip_bfloat16 h; u16 u; } cv;
    cv.h = __float2bfloat16(f);
    return cv.u;
}
__device__ inline float bf2f(u16 v){ return __uint_as_float(((unsigned)v) << 16); }

__device__ inline void gld16b(const void* g, void* l){
    __builtin_amdgcn_global_load_lds(
        (const __attribute__((address_space(1))) unsigned int*)g,
        (__attribute__((address_space(3))) unsigned int*)l, 16, 0, 0);
}

__device__ inline float wredS(float v){
    #pragma unroll
    for (int o = 32; o; o >>= 1) v += __shfl_xor(v, o, 64);
    return v;
}
__device__ inline float wredM(float v){
    #pragma unroll
    for (int o = 32; o; o >>= 1) v = fmaxf(v, __shfl_xor(v, o, 64));
    return v;
}

// ---------------------------------------------------------------------------
// K0: adj transpose (int -> i8 {0,1} + self-loops) + column-degree sums.
// ---------------------------------------------------------------------------
__global__ __launch_bounds__(256) void k_prep(const int* __restrict__ adj,
                                              i8* __restrict__ ATi8,
                                              float* __restrict__ degF){
    int i0 = blockIdx.x * 64, j0 = blockIdx.y * 64, b = blockIdx.z;
    __shared__ i8 tile[64 * 80];
    __shared__ float degP[256];
    int t = threadIdx.x;
    const int* ap = adj + (size_t)b * N_ * N_;
    #pragma unroll
    for (int it = 0; it < 4; ++it){
        int jj = it * 16 + (t >> 4);
        int gi0 = (t & 15) * 4;
        int4 a4 = *(const int4*)&ap[(size_t)(j0 + jj) * N_ + i0 + gi0];
        int gj = j0 + jj;
        tile[(gi0 + 0) * 80 + jj] = (a4.x != 0 || gj == i0 + gi0 + 0) ? 1 : 0;
        tile[(gi0 + 1) * 80 + jj] = (a4.y != 0 || gj == i0 + gi0 + 1) ? 1 : 0;
        tile[(gi0 + 2) * 80 + jj] = (a4.z != 0 || gj == i0 + gi0 + 2) ? 1 : 0;
        tile[(gi0 + 3) * 80 + jj] = (a4.w != 0 || gj == i0 + gi0 + 3) ? 1 : 0;
    }
    __syncthreads();
    {
        int ii = t & 63, q = t >> 6;
        float s = 0.f;
        #pragma unroll
        for (int k = 0; k < 16; ++k) s += (float)tile[ii * 80 + q * 16 + k];
        degP[t] = s;
    }
    __syncthreads();
    if (t < 64){
        float s = degP[t] + degP[t + 64] + degP[t + 128] + degP[t + 192];
        atomicAdd(&degF[b * N_ + i0 + t], s);
    }
    i8* op = ATi8 + (size_t)b * N_ * N_;
    {
        int io = t >> 2, slot = (t & 3) * 16;
        *(uint4*)&op[(size_t)(i0 + io) * N_ + j0 + slot] = *(const uint4*)&tile[io * 80 + slot];
    }
}

// ---------------------------------------------------------------------------
struct MegaArgs {
    const float *feat; const int *cand; const int *act;
    const float *W1, *b1, *W2, *b2, *W3, *b3, *ms;
    const float *A1, *ab1, *A2, *ab2, *A3, *ab3;
    const float *C1, *cb1, *C2, *cb2;
    const i8 *ATi8;
    float *degF, *poolF; int *absm;     // absm[0..15] stage2, [16..31] stage3
    float *m01, *invs1, *cvec, *scr;
    u16 *Yb16, *hbuf, *WT2, *WT3, *A1aT, *A2T;
    i8 *Yq1, *Yq2;
    float *out;
};

// ---------------------------------------------------------------------------
// P1: featmax (bx<16) + weight transposes (bx 16..271)
// ---------------------------------------------------------------------------
__device__ void dev_p1(const MegaArgs& a, int bx, int t, char* smem){
    if (bx < 16){
        int b = bx;
        float lm0 = 0.f, lm1 = 0.f;
        #pragma unroll
        for (int it = 0; it < 8; ++it){
            int j = it * 256 + t;
            float dsj = rsqrtf(a.degF[b * N_ + j]);
            lm0 = fmaxf(lm0, dsj * fabsf(a.feat[((size_t)b * N_ + j) * 2 + 0]));
            lm1 = fmaxf(lm1, dsj * fabsf(a.feat[((size_t)b * N_ + j) * 2 + 1]));
        }
        float* r0 = (float*)smem;
        float* r1 = (float*)(smem + 1024);
        r0[t] = lm0; r1[t] = lm1;
        __syncthreads();
        if (t < 128){ r0[t] = fmaxf(r0[t], r0[t + 128]); r1[t] = fmaxf(r1[t], r1[t + 128]); }
        __syncthreads();
        if (t < 64){
            float m0 = wredM(fmaxf(r0[t], r0[t + 64]));
            float m1 = wredM(fmaxf(r1[t], r1[t + 64]));
            if (t == 0){ a.m01[b * 2] = m0; a.m01[b * 2 + 1] = m1; }
        }
        __syncthreads();
    } else if (bx < 272){
        int q = (bx - 16) >> 6;
        const float* s; u16* d;
        switch (q){
            case 0: s = a.W2; d = a.WT2; break;
            case 1: s = a.W3; d = a.WT3; break;
            case 2: s = a.A1; d = a.A1aT; break;
            default: s = a.A2; d = a.A2T; break;
        }
        int idx = ((bx - 16) & 63) * 256 + t;
        int hp = idx >> 7, k = idx & 127;
        d[hp * 128 + k] = f2bf(s[k * 128 + hp]);
    }
}

// ---------------------------------------------------------------------------
// P2: Y1 quantized directly, analytic per-h bound
// ---------------------------------------------------------------------------
__device__ void dev_y1q(const MegaArgs& a, int vb, int t){
    int b = vb & 15, seg = vb >> 4;       // seg 0..31 -> 4 h rows
    float m0 = a.m01[b * 2], m1 = a.m01[b * 2 + 1];
    int j0 = t * 8;
    float4 f4[4];
    #pragma unroll
    for (int k = 0; k < 4; ++k)
        f4[k] = *(const float4*)&a.feat[((size_t)b * N_ + j0) * 2 + k * 4];
    const float* ff = (const float*)f4;
    float dsj[8];
    #pragma unroll
    for (int e = 0; e < 8; ++e) dsj[e] = rsqrtf(a.degF[b * N_ + j0 + e]);
    #pragma unroll
    for (int hh = 0; hh < 4; ++hh){
        int h = seg * 4 + hh;
        float w0 = a.W1[h], w1 = a.W1[H_ + h];
        float bound = m0 * fabsf(w0) + m1 * fabsf(w1);
        float s = (bound > 0.f) ? 126.f / bound : 0.f;
        if (t == 0) a.invs1[b * H_ + h] = bound * (1.f / 126.f);
        int q[8];
        #pragma unroll
        for (int e = 0; e < 8; ++e){
            float v = dsj[e] * (ff[2 * e] * w0 + ff[2 * e + 1] * w1);
            q[e] = (int)rintf(v * s);
        }
        unsigned lo = (q[0] & 255) | ((q[1] & 255) << 8) | ((q[2] & 255) << 16) | ((unsigned)(q[3] & 255) << 24);
        unsigned hi = (q[4] & 255) | ((q[5] & 255) << 8) | ((q[6] & 255) << 16) | ((unsigned)(q[7] & 255) << 24);
        *(uint2*)&a.Yq1[(size_t)b * H_ * N_ + (size_t)h * N_ + j0] = make_uint2(lo, hi);
    }
}

// ---------------------------------------------------------------------------
// GCN layer phase. Phase-1 i8 GEMM M=64,N=128,K=2048 (LDS As/Bs swizzled).
// Phase-2 (MODE=0): bf16 MFMA, W fragments DIRECT FROM GLOBAL (L2-hot).
// MODE=1: h3 + pool.  LDS: As 4K | Bs 8K | Hs 17408 | pmax 1K = 30720.
// ---------------------------------------------------------------------------
template<int PER_N, int MODE>
__device__ void layer_phase(const MegaArgs& a, int vbid, int t,
                            const i8* __restrict__ Yq,
                            const float* __restrict__ bias,
                            const int* __restrict__ absmIn,
                            const u16* __restrict__ WTg,
                            u16* __restrict__ Yout, int* __restrict__ absmBase,
                            char* smem){
    int b = vbid & 15, i0 = (vbid >> 4) * 64;
    const i8* Ab = a.ATi8 + (size_t)b * N_ * N_ + (size_t)i0 * N_;
    const i8* Bb = Yq + (size_t)b * H_ * N_;
    i8*  As = (i8*)smem;
    i8*  Bs = (i8*)(smem + 4096);
    u16* Hs = (u16*)(smem + 12288);            // 64*136*2 = 17408
    float* pmax = (float*)(smem + 29696);
    int w = t >> 6, lane = t & 63, quad = lane >> 4, l16 = lane & 15;
    int mr = w & 1, nc = w >> 1;

    float inv_s = PER_N ? 0.f : __int_as_float(absmIn[b]) * (1.f / 126.f);
    const float* invN = PER_N ? (a.invs1 + b * H_) : nullptr;

    v4i acc[2][4];
    #pragma unroll
    for (int mt = 0; mt < 2; ++mt)
        #pragma unroll
        for (int nt = 0; nt < 4; ++nt) acc[mt][nt] = (v4i){0, 0, 0, 0};

    int srow = lane & 15;
    int sslot = ((lane >> 4) ^ (lane & 3)) * 16;
    int fxo = (quad ^ (l16 & 3)) * 256 + l16 * 16;

    for (int k0 = 0; k0 < N_; k0 += 64){
        #pragma unroll
        for (int it = 0; it < 3; ++it){
            int g = w * 3 + it;
            if (g < 4)
                gld16b(Ab + (size_t)(g * 16 + srow) * N_ + k0 + sslot, As + g * 1024);
            else
                gld16b(Bb + (size_t)((g - 4) * 16 + srow) * N_ + k0 + sslot, Bs + (g - 4) * 1024);
        }
        __syncthreads();
        v4i af[2];
        #pragma unroll
        for (int mt = 0; mt < 2; ++mt)
            af[mt] = *(const v4i*)&As[(mr * 2 + mt) * 1024 + fxo];
        #pragma unroll
        for (int nt = 0; nt < 4; ++nt){
            v4i bv = *(const v4i*)&Bs[(nc * 4 + nt) * 1024 + fxo];
            #pragma unroll
            for (int mt = 0; mt < 2; ++mt)
                acc[mt][nt] = __builtin_amdgcn_mfma_i32_16x16x64_i8(af[mt], bv, acc[mt][nt], 0, 0, 0);
        }
        __syncthreads();
    }

    // epilogue 1: h = relu(dis_i * dequant(acc) + bias) -> Hs
    #pragma unroll
    for (int mt = 0; mt < 2; ++mt)
        #pragma unroll
        for (int r = 0; r < 4; ++r){
            int m = mr * 32 + mt * 16 + quad * 4 + r;
            float dsc = rsqrtf(a.degF[b * N_ + i0 + m]);
            #pragma unroll
            for (int nt = 0; nt < 4; ++nt){
                int n = nc * 64 + nt * 16 + l16;
                float z = (float)acc[mt][nt][r] * (PER_N ? invN[n] : inv_s);
                float v = dsc * z + bias[n];
                Hs[m * 136 + n] = f2bf(v > 0.f ? v : 0.f);
            }
        }
    __syncthreads();

    if (MODE == 0){
        // phase 2: Z2[m,h'] = sum_k Hs[m,k] * WT[h',k]; W frags direct global
        f32x4 a2[2][4];
        #pragma unroll
        for (int mt = 0; mt < 2; ++mt)
            #pragma unroll
            for (int nt = 0; nt < 4; ++nt) a2[mt][nt] = (f32x4){0.f, 0.f, 0.f, 0.f};
        #pragma unroll
        for (int kc = 0; kc < 4; ++kc){
            bf16x8 af[2];
            #pragma unroll
            for (int mt = 0; mt < 2; ++mt)
                af[mt] = *(const bf16x8*)&Hs[(mr * 32 + mt * 16 + l16) * 136 + kc * 32 + quad * 8];
            #pragma unroll
            for (int nt = 0; nt < 4; ++nt){
                bf16x8 bv = *(const bf16x8*)&WTg[(size_t)(nc * 64 + nt * 16 + l16) * H_ + kc * 32 + quad * 8];
                #pragma unroll
                for (int mt = 0; mt < 2; ++mt)
                    a2[mt][nt] = __builtin_amdgcn_mfma_f32_16x16x32_bf16(af[mt], bv, a2[mt][nt], 0, 0, 0);
            }
        }
        __syncthreads();
        float lmax = 0.f;
        #pragma unroll
        for (int mt = 0; mt < 2; ++mt)
            #pragma unroll
            for (int r = 0; r < 4; ++r){
                int m = mr * 32 + mt * 16 + quad * 4 + r;
                float dsc = rsqrtf(a.degF[b * N_ + i0 + m]);
                #pragma unroll
                for (int nt = 0; nt < 4; ++nt){
                    float v = dsc * a2[mt][nt][r];
                    lmax = fmaxf(lmax, fabsf(v));
                    Hs[m * 136 + nc * 64 + nt * 16 + l16] = f2bf(v);
                }
            }
        pmax[t] = lmax;
        __syncthreads();
        size_t obase = (size_t)b * H_ * N_ + i0;
        int j = t & 63, hq = t >> 6;
        #pragma unroll 8
        for (int rep = 0; rep < 32; ++rep){
            int hrow = hq * 32 + rep;
            Yout[obase + (size_t)hrow * N_ + j] = Hs[j * 136 + hrow];
        }
        if (t < 64){
            float mv = fmaxf(fmaxf(pmax[t], pmax[t + 64]), fmaxf(pmax[t + 128], pmax[t + 192]));
            mv = wredM(mv);
            if (t == 0) atomicMax(absmBase + b, __float_as_int(mv));
        }
    } else {
        #pragma unroll
        for (int rep = 0; rep < 4; ++rep){
            int e = rep * 256 + t;
            int row = e >> 4, c8 = e & 15;
            *(uint4*)&a.hbuf[((size_t)b * N_ + i0 + row) * H_ + c8 * 8] = *(const uint4*)&Hs[row * 136 + c8 * 8];
        }
        int n = t & 127, rq = t >> 7;
        float ps = 0.f;
        #pragma unroll 8
        for (int r = 0; r < 32; ++r) ps += bf2f(Hs[(rq * 32 + r) * 136 + n]);
        pmax[t] = ps;
        __syncthreads();
        if (t < 128)
            atomicAdd(&a.poolF[b * H_ + t], (pmax[t] + pmax[t + 128]) * (1.f / N_));
    }
    __syncthreads();
}

// quantize Yb16 -> Yq; stage 0: absm[0..15]->Yq2, stage 1: absm[16..31]->Yq1
__device__ void dev_quant(const MegaArgs& a, int stage, int vb, int t){
    const int* am = a.absm + stage * 16;
    i8* dst = stage ? a.Yq1 : a.Yq2;
    int idx = vb * 256 + t;
    #pragma unroll
    for (int it = 0; it < 4; ++it){
        int pos = (it * 131072 + idx) * 8;
        int b = pos >> 18;
        float m = __int_as_float(am[b]);
        float s = (m > 0.f) ? 126.f / m : 0.f;
        bf16x8 y = *(const bf16x8*)&a.Yb16[pos];
        int q[8];
        #pragma unroll
        for (int e = 0; e < 8; ++e) q[e] = (int)rintf(bf2f((u16)y[e]) * s);
        unsigned lo = (q[0] & 255) | ((q[1] & 255) << 8) | ((q[2] & 255) << 16) | ((unsigned)(q[3] & 255) << 24);
        unsigned hi = (q[4] & 255) | ((q[5] & 255) << 8) | ((q[6] & 255) << 16) | ((unsigned)(q[7] & 255) << 24);
        *(uint2*)&dst[pos] = make_uint2(lo, hi);
    }
}

// cvec + value head (b < 16)
__device__ void dev_cv(const MegaArgs& a, int b, int t, char* smem){
    float* pl  = (float*)smem;
    float* msl = (float*)(smem + 512);
    float* v1  = (float*)(smem + 1024);
    if (t < 128){ pl[t] = a.poolF[b * H_ + t]; msl[t] = a.ms[t]; }
    __syncthreads();
    if (t < 128){
        float c = a.ab1[t];
        for (int k = 0; k < 128; ++k)
            c += pl[k] * a.A1[(128 + k) * H_ + t] + msl[k] * a.A1[(256 + k) * H_ + t];
        a.cvec[b * H_ + t] = c;
    } else if (t < 160){
        int cc = t - 128;
        float v = a.cb1[cc];
        for (int k = 0; k < 128; ++k) v += pl[k] * a.C1[k * CH_ + cc];
        v1[cc] = v > 0.f ? v : 0.f;
    }
    __syncthreads();
    if (t == 0){
        float v = a.cb2[0];
        for (int c = 0; c < CH_; ++c) v += v1[c] * a.C2[c];
        a.out[48 + b] = v;
    }
    __syncthreads();
}

// actor MLP, 64-row wave-local tiles; B operands direct from global.
// LDS: M1 only (17408). No cross-wave smem -> no barriers.
__device__ void dev_actor(const MegaArgs& a, int vbid, int t, char* smem){
    int b = vbid & 15, i0 = (vbid >> 4) * 64;
    const u16* Ab = a.hbuf + ((size_t)b * N_ + i0) * H_;
    u16* M1 = (u16*)smem;
    int w = t >> 6, lane = t & 63, quad = lane >> 4, l16 = lane & 15;
    f32x4 acc[8];
    #pragma unroll
    for (int nt = 0; nt < 8; ++nt) acc[nt] = (f32x4){0.f, 0.f, 0.f, 0.f};
    // GEMM1: h3 @ A1a  (A and B frags direct from global)
    #pragma unroll
    for (int kc = 0; kc < 4; ++kc){
        bf16x8 af = *(const bf16x8*)&Ab[(size_t)(w * 16 + l16) * H_ + kc * 32 + quad * 8];
        #pragma unroll
        for (int nt = 0; nt < 8; ++nt){
            bf16x8 bv = *(const bf16x8*)&a.A1aT[(size_t)(nt * 16 + l16) * H_ + kc * 32 + quad * 8];
            acc[nt] = __builtin_amdgcn_mfma_f32_16x16x32_bf16(af, bv, acc[nt], 0, 0, 0);
        }
    }
    const float* cv = a.cvec + b * H_;
    #pragma unroll
    for (int r = 0; r < 4; ++r){
        int m = w * 16 + quad * 4 + r;
        #pragma unroll
        for (int nt = 0; nt < 8; ++nt){
            int n = nt * 16 + l16;
            float v = acc[nt][r] + cv[n];
            M1[m * 136 + n] = f2bf(v > 0.f ? v : 0.f);
            acc[nt][r] = 0.f;
        }
    }
    // GEMM2: a1 @ A2 (A frag from M1 — wave-local rows; B direct global)
    #pragma unroll
    for (int kc = 0; kc < 4; ++kc){
        bf16x8 af = *(const bf16x8*)&M1[(w * 16 + l16) * 136 + kc * 32 + quad * 8];
        #pragma unroll
        for (int nt = 0; nt < 8; ++nt){
            bf16x8 bv = *(const bf16x8*)&a.A2T[(size_t)(nt * 16 + l16) * H_ + kc * 32 + quad * 8];
            acc[nt] = __builtin_amdgcn_mfma_f32_16x16x32_bf16(af, bv, acc[nt], 0, 0, 0);
        }
    }
    float ab3v = a.ab3[0];
    #pragma unroll
    for (int r = 0; r < 4; ++r){
        int m = w * 16 + quad * 4 + r;
        float part = 0.f;
        #pragma unroll
        for (int nt = 0; nt < 8; ++nt){
            int n = nt * 16 + l16;
            float v = acc[nt][r] + a.ab2[n];
            v = v > 0.f ? v : 0.f;
            part += v * a.A3[n];
        }
        #pragma unroll
        for (int o = 1; o < 16; o <<= 1) part += __shfl_xor(part, o, 64);
        if (l16 == 0) a.scr[(size_t)b * N_ + i0 + m] = (part + ab3v) * 10.f;
    }
    __syncthreads();
}

// softmax / masked log_softmax / entropy (b < 16)
__device__ void dev_sm(const MegaArgs& a, int b, int t, char* smem){
    float* sc  = (float*)smem;
    float* red = (float*)(smem + 8192);
    float* lps = (float*)(smem + 8256);
    const float* sp = a.scr + (size_t)b * N_;
    const int*   cp = a.cand + (size_t)b * N_;
    float mx = -1e30f;
    for (int i = t; i < N_; i += 256){ float v = sp[i]; sc[i] = v; mx = fmaxf(mx, v); }
    mx = wredM(mx);
    if ((t & 63) == 0) red[t >> 6] = mx;
    __syncthreads();
    mx = fmaxf(fmaxf(red[0], red[1]), fmaxf(red[2], red[3]));
    __syncthreads();
    float se = 0.f;
    for (int i = t; i < N_; i += 256) se += expf(sc[i] - mx);
    se = wredS(se);
    if ((t & 63) == 0) red[t >> 6] = se;
    __syncthreads();
    float s1 = red[0] + red[1] + red[2] + red[3];
    __syncthreads();
    float inv = 1.f / s1;
    float m2 = -1e30f;
    for (int i = t; i < N_; i += 256){
        float p = expf(sc[i] - mx) * inv;
        sc[i] = p;
        if (cp[i] != 0) m2 = fmaxf(m2, p);
    }
    m2 = wredM(m2);
    if ((t & 63) == 0) red[t >> 6] = m2;
    __syncthreads();
    m2 = fmaxf(fmaxf(red[0], red[1]), fmaxf(red[2], red[3]));
    __syncthreads();
    float s2 = 0.f;
    for (int i = t; i < N_; i += 256) if (cp[i] != 0) s2 += expf(sc[i] - m2);
    s2 = wredS(s2);
    if ((t & 63) == 0) red[t >> 6] = s2;
    __syncthreads();
    float lse = m2 + logf(red[0] + red[1] + red[2] + red[3]);
    __syncthreads();
    int ac = a.act[b];
    float ent = 0.f;
    for (int i = t; i < N_; i += 256){
        float lp = (cp[i] != 0 ? sc[i] : NEG_) - lse;
        float pe = expf(lp);
        ent -= pe * lp;
        if (i == ac) *lps = lp;
    }
    ent = wredS(ent);
    if ((t & 63) == 0) red[t >> 6] = ent;
    __syncthreads();
    if (t == 0){
        a.out[b]      = (float)ac;
        a.out[16 + b] = *lps;
        a.out[32 + b] = red[0] + red[1] + red[2] + red[3];
    }
}

// ---------------------------------------------------------------------------
// MEGA: cooperative, grid-size agnostic (512 or 256 blocks).
// ---------------------------------------------------------------------------
__global__ __launch_bounds__(256, 2) void k_mega(MegaArgs a){
    cg::grid_group grid = cg::this_grid();
    __shared__ __align__(16) char smem[30720];
    int bid = blockIdx.x, t = threadIdx.x, G = gridDim.x;

    for (int bx = bid; bx < 272; bx += G) dev_p1(a, bx, t, smem);
    grid.sync();
    for (int vb = bid; vb < 512; vb += G) dev_y1q(a, vb, t);
    grid.sync();
    for (int vb = bid; vb < 512; vb += G)
        layer_phase<1, 0>(a, vb, t, a.Yq1, a.b1, nullptr, a.WT2, a.Yb16, a.absm, smem);
    grid.sync();
    for (int vb = bid; vb < 512; vb += G) dev_quant(a, 0, vb, t);
    grid.sync();
    for (int vb = bid; vb < 512; vb += G)
        layer_phase<0, 0>(a, vb, t, a.Yq2, a.b2, a.absm, a.WT3, a.Yb16, a.absm + 16, smem);
    grid.sync();
    for (int vb = bid; vb < 512; vb += G) dev_quant(a, 1, vb, t);
    grid.sync();
    for (int vb = bid; vb < 512; vb += G)
        layer_phase<0, 1>(a, vb, t, a.Yq1, a.b3, a.absm + 16, nullptr, nullptr, nullptr, smem);
    grid.sync();
    if (bid < 16) dev_cv(a, bid, t, smem);
    grid.sync();
    for (int vb = bid; vb < 512; vb += G) dev_actor(a, vb, t, smem);
    grid.sync();
    if (bid < 16) dev_sm(a, bid, t, smem);
}

// ---------------------------------------------------------------------------
// Fallback wrappers (non-cooperative) — same device code, separate launches.
// ---------------------------------------------------------------------------
__global__ __launch_bounds__(256) void f_p1(MegaArgs a){
    __shared__ __align__(16) char sm[2048];
    dev_p1(a, blockIdx.x, threadIdx.x, sm);
}
__global__ __launch_bounds__(256) void f_y1q(MegaArgs a){
    dev_y1q(a, blockIdx.x, threadIdx.x);
}
__global__ __launch_bounds__(256, 2) void f_l1(MegaArgs a){
    __shared__ __align__(16) char sm[30720];
    layer_phase<1, 0>(a, blockIdx.x, threadIdx.x, a.Yq1, a.b1, nullptr, a.WT2, a.Yb16, a.absm, sm);
}
__global__ __launch_bounds__(256, 2) void f_l2(MegaArgs a){
    __shared__ __align__(16) char sm[30720];
    layer_phase<0, 0>(a, blockIdx.x, threadIdx.x, a.Yq2, a.b2, a.absm, a.WT3, a.Yb16, a.absm + 16, sm);
}
__global__ __launch_bounds__(256, 2) void f_l3(MegaArgs a){
    __shared__ __align__(16) char sm[30720];
    layer_phase<0, 1>(a, blockIdx.x, threadIdx.x, a.Yq1, a.b3, a.absm + 16, nullptr, nullptr, nullptr, sm);
}
template<int S>
__global__ __launch_bounds__(256) void f_q(MegaArgs a){
    dev_quant(a, S, blockIdx.x, threadIdx.x);
}
__global__ __launch_bounds__(256) void f_cv(MegaArgs a){
    __shared__ __align__(16) char sm[2048];
    dev_cv(a, blockIdx.x, threadIdx.x, sm);
}
__global__ __launch_bounds__(256) void f_actor(MegaArgs a){
    __shared__ __align__(16) char sm[17408];
    dev_actor(a, blockIdx.x, threadIdx.x, sm);
}
__global__ __launch_bounds__(256) void f_sm(MegaArgs a){
    __shared__ __align__(16) char sm[8320];
    dev_sm(a, blockIdx.x, threadIdx.x, sm);
}

// ---------------------------------------------------------------------------
extern "C" void kernel_launch(void* const* d_in, const int* in_sizes, int n_in,
                              void* d_out, int out_size, void* d_ws, size_t ws_size,
                              hipStream_t stream) {
    const float* feat = (const float*)d_in[0];
    const int*   adj  = (const int*)d_in[1];

    char* w8 = (char*)d_ws;
    size_t off = 0;
    auto alloc = [&](size_t bytes){ void* p = w8 + off; off += (bytes + 255) & ~(size_t)255; return p; };
    i8*    ATi8  = (i8*)   alloc((size_t)B_ * N_ * N_);
    u16*   Yb16  = (u16*)  alloc((size_t)B_ * H_ * N_ * 2);
    i8*    Yq1   = (i8*)   alloc((size_t)B_ * H_ * N_);
    i8*    Yq2   = (i8*)   alloc((size_t)B_ * H_ * N_);
    u16*   hbuf  = (u16*)  alloc((size_t)B_ * N_ * H_ * 2);
    float* degF  = (float*)alloc((size_t)B_ * N_ * 4);      // zeroed
    float* poolF = (float*)alloc((size_t)B_ * H_ * 4);      // zeroed
    int*   absm  = (int*)  alloc(256);                      // zeroed
    float* m01   = (float*)alloc(32 * 4);
    float* invs1 = (float*)alloc((size_t)B_ * H_ * 4);
    float* cvec  = (float*)alloc((size_t)B_ * H_ * 4);
    float* scr   = (float*)alloc((size_t)B_ * N_ * 4);
    u16*   WT2   = (u16*)  alloc((size_t)H_ * H_ * 2);
    u16*   WT3   = (u16*)  alloc((size_t)H_ * H_ * 2);
    u16*   A1aT  = (u16*)  alloc((size_t)H_ * H_ * 2);
    u16*   A2T   = (u16*)  alloc((size_t)H_ * H_ * 2);

    hipMemsetAsync(degF, 0, (size_t)B_ * N_ * 4 + (size_t)B_ * H_ * 4 + 256, stream);

    k_prep<<<dim3(32, 32, 16), 256, 0, stream>>>(adj, ATi8, degF);

    MegaArgs ma;
    ma.feat = feat; ma.cand = (const int*)d_in[2]; ma.act = (const int*)d_in[3];
    ma.W1 = (const float*)d_in[4];  ma.b1 = (const float*)d_in[5];
    ma.W2 = (const float*)d_in[6];  ma.b2 = (const float*)d_in[7];
    ma.W3 = (const float*)d_in[8];  ma.b3 = (const float*)d_in[9];
    ma.ms = (const float*)d_in[10];
    ma.A1 = (const float*)d_in[11]; ma.ab1 = (const float*)d_in[12];
    ma.A2 = (const float*)d_in[13]; ma.ab2 = (const float*)d_in[14];
    ma.A3 = (const float*)d_in[15]; ma.ab3 = (const float*)d_in[16];
    ma.C1 = (const float*)d_in[17]; ma.cb1 = (const float*)d_in[18];
    ma.C2 = (const float*)d_in[19]; ma.cb2 = (const float*)d_in[20];
    ma.ATi8 = ATi8; ma.degF = degF; ma.poolF = poolF; ma.absm = absm;
    ma.m01 = m01; ma.invs1 = invs1; ma.cvec = cvec; ma.scr = scr;
    ma.Yb16 = Yb16; ma.hbuf = hbuf; ma.WT2 = WT2; ma.WT3 = WT3;
    ma.A1aT = A1aT; ma.A2T = A2T; ma.Yq1 = Yq1; ma.Yq2 = Yq2;
    ma.out = (float*)d_out;

    void* params[] = { &ma };
    hipError_t ce = hipLaunchCooperativeKernel((void*)k_mega, dim3(512), dim3(256),
                                               params, 0, stream);
    if (ce != hipSuccess){
        (void)hipGetLastError();
        ce = hipLaunchCooperativeKernel((void*)k_mega, dim3(256), dim3(256),
                                        params, 0, stream);
    }
    if (ce != hipSuccess){
        (void)hipGetLastError();
        f_p1   <<<dim3(272), 256, 0, stream>>>(ma);
        f_y1q  <<<dim3(512), 256, 0, stream>>>(ma);
        f_l1   <<<dim3(512), 256, 0, stream>>>(ma);
        f_q<0> <<<dim3(512), 256, 0, stream>>>(ma);
        f_l2   <<<dim3(512), 256, 0, stream>>>(ma);
        f_q<1> <<<dim3(512), 256, 0, stream>>>(ma);
        f_l3   <<<dim3(512), 256, 0, stream>>>(ma);
        f_cv   <<<dim3(16),  256, 0, stream>>>(ma);
        f_actor<<<dim3(512), 256, 0, stream>>>(ma);
        f_sm   <<<dim3(16),  256, 0, stream>>>(ma);
    }
}

// Round 7
// 549.685 us; speedup vs baseline: 1.8836x; 1.8836x over previous
//
#include <hip/hip_runtime.h>
#include <hip/hip_bf16.h>
#include <stdint.h>

#define B_  16
#define N_  2048
#define D_  2
#define H_  128
#define CH_ 32
#define NEG_ (-1e9f)

typedef __attribute__((ext_vector_type(8))) short bf16x8;
typedef __attribute__((ext_vector_type(4))) float f32x4;
typedef __attribute__((ext_vector_type(4))) int   v4i;
typedef unsigned short u16;
typedef signed char    i8;

__device__ inline u16 f2bf(float f){
    union { __hip_bfloat16 h; u16 u; } cv;
    cv.h = __float2bfloat16(f);
    return cv.u;
}
__device__ inline float bf2f(u16 v){ return __uint_as_float(((unsigned)v) << 16); }

__device__ inline void gld16b(const void* g, void* l){
    __builtin_amdgcn_global_load_lds(
        (const __attribute__((address_space(1))) unsigned int*)g,
        (__attribute__((address_space(3))) unsigned int*)l, 16, 0, 0);
}

__device__ inline float wredS(float v){
    #pragma unroll
    for (int o = 32; o; o >>= 1) v += __shfl_xor(v, o, 64);
    return v;
}
__device__ inline float wredM(float v){
    #pragma unroll
    for (int o = 32; o; o >>= 1) v = fmaxf(v, __shfl_xor(v, o, 64));
    return v;
}

// ---------------------------------------------------------------------------
// K0: adj transpose (int -> i8 {0,1} + self-loops) + column-degree sums.
// ---------------------------------------------------------------------------
__global__ __launch_bounds__(256) void k_prep(const int* __restrict__ adj,
                                              i8* __restrict__ ATi8,
                                              float* __restrict__ degF){
    int i0 = blockIdx.x * 64, j0 = blockIdx.y * 64, b = blockIdx.z;
    __shared__ i8 tile[64 * 80];
    __shared__ float degP[256];
    int t = threadIdx.x;
    const int* ap = adj + (size_t)b * N_ * N_;
    #pragma unroll
    for (int it = 0; it < 4; ++it){
        int jj = it * 16 + (t >> 4);
        int gi0 = (t & 15) * 4;
        int4 a4 = *(const int4*)&ap[(size_t)(j0 + jj) * N_ + i0 + gi0];
        int gj = j0 + jj;
        tile[(gi0 + 0) * 80 + jj] = (a4.x != 0 || gj == i0 + gi0 + 0) ? 1 : 0;
        tile[(gi0 + 1) * 80 + jj] = (a4.y != 0 || gj == i0 + gi0 + 1) ? 1 : 0;
        tile[(gi0 + 2) * 80 + jj] = (a4.z != 0 || gj == i0 + gi0 + 2) ? 1 : 0;
        tile[(gi0 + 3) * 80 + jj] = (a4.w != 0 || gj == i0 + gi0 + 3) ? 1 : 0;
    }
    __syncthreads();
    {
        int ii = t & 63, q = t >> 6;
        float s = 0.f;
        #pragma unroll
        for (int k = 0; k < 16; ++k) s += (float)tile[ii * 80 + q * 16 + k];
        degP[t] = s;
    }
    __syncthreads();
    if (t < 64){
        float s = degP[t] + degP[t + 64] + degP[t + 128] + degP[t + 192];
        atomicAdd(&degF[b * N_ + i0 + t], s);
    }
    i8* op = ATi8 + (size_t)b * N_ * N_;
    {
        int io = t >> 2, slot = (t & 3) * 16;
        *(uint4*)&op[(size_t)(i0 + io) * N_ + j0 + slot] = *(const uint4*)&tile[io * 80 + slot];
    }
}

// ---------------------------------------------------------------------------
struct MegaArgs {
    const float *feat; const int *cand; const int *act;
    const float *W1, *b1, *W2, *b2, *W3, *b3, *ms;
    const float *A1, *ab1, *A2, *ab2, *A3, *ab3;
    const float *C1, *cb1, *C2, *cb2;
    const i8 *ATi8;
    float *degF, *poolF; int *absm;     // absm[0..15] stage2, [16..31] stage3
    float *m01, *invs1, *scr;
    u16 *Yb16, *hbuf, *WT2, *WT3, *A1aT, *A2T;
    i8 *Yq1, *Yq2;
    float *out;
};

// ---------------------------------------------------------------------------
// P1: featmax (bx<16) + weight transposes (bx 16..271)
// ---------------------------------------------------------------------------
__global__ __launch_bounds__(256) void f_p1(MegaArgs a){
    __shared__ float r0[256], r1[256];
    int bx = blockIdx.x, t = threadIdx.x;
    if (bx < 16){
        int b = bx;
        float lm0 = 0.f, lm1 = 0.f;
        #pragma unroll
        for (int it = 0; it < 8; ++it){
            int j = it * 256 + t;
            float dsj = rsqrtf(a.degF[b * N_ + j]);
            lm0 = fmaxf(lm0, dsj * fabsf(a.feat[((size_t)b * N_ + j) * 2 + 0]));
            lm1 = fmaxf(lm1, dsj * fabsf(a.feat[((size_t)b * N_ + j) * 2 + 1]));
        }
        r0[t] = lm0; r1[t] = lm1;
        __syncthreads();
        if (t < 128){ r0[t] = fmaxf(r0[t], r0[t + 128]); r1[t] = fmaxf(r1[t], r1[t + 128]); }
        __syncthreads();
        if (t < 64){
            float m0 = wredM(fmaxf(r0[t], r0[t + 64]));
            float m1 = wredM(fmaxf(r1[t], r1[t + 64]));
            if (t == 0){ a.m01[b * 2] = m0; a.m01[b * 2 + 1] = m1; }
        }
    } else {
        int q = (bx - 16) >> 6;
        const float* s; u16* d;
        switch (q){
            case 0: s = a.W2; d = a.WT2; break;
            case 1: s = a.W3; d = a.WT3; break;
            case 2: s = a.A1; d = a.A1aT; break;
            default: s = a.A2; d = a.A2T; break;
        }
        int idx = ((bx - 16) & 63) * 256 + t;
        int hp = idx >> 7, k = idx & 127;
        d[hp * 128 + k] = f2bf(s[k * 128 + hp]);
    }
}

// ---------------------------------------------------------------------------
// P2: Y1 quantized directly, analytic per-h bound
// ---------------------------------------------------------------------------
__global__ __launch_bounds__(256) void f_y1q(MegaArgs a){
    int vb = blockIdx.x, t = threadIdx.x;
    int b = vb & 15, seg = vb >> 4;       // seg 0..31 -> 4 h rows
    float m0 = a.m01[b * 2], m1 = a.m01[b * 2 + 1];
    int j0 = t * 8;
    float4 f4[4];
    #pragma unroll
    for (int k = 0; k < 4; ++k)
        f4[k] = *(const float4*)&a.feat[((size_t)b * N_ + j0) * 2 + k * 4];
    const float* ff = (const float*)f4;
    float dsj[8];
    #pragma unroll
    for (int e = 0; e < 8; ++e) dsj[e] = rsqrtf(a.degF[b * N_ + j0 + e]);
    #pragma unroll
    for (int hh = 0; hh < 4; ++hh){
        int h = seg * 4 + hh;
        float w0 = a.W1[h], w1 = a.W1[H_ + h];
        float bound = m0 * fabsf(w0) + m1 * fabsf(w1);
        float s = (bound > 0.f) ? 126.f / bound : 0.f;
        if (t == 0) a.invs1[b * H_ + h] = bound * (1.f / 126.f);
        int q[8];
        #pragma unroll
        for (int e = 0; e < 8; ++e){
            float v = dsj[e] * (ff[2 * e] * w0 + ff[2 * e + 1] * w1);
            q[e] = (int)rintf(v * s);
        }
        unsigned lo = (q[0] & 255) | ((q[1] & 255) << 8) | ((q[2] & 255) << 16) | ((unsigned)(q[3] & 255) << 24);
        unsigned hi = (q[4] & 255) | ((q[5] & 255) << 8) | ((q[6] & 255) << 16) | ((unsigned)(q[7] & 255) << 24);
        *(uint2*)&a.Yq1[(size_t)b * H_ * N_ + (size_t)h * N_ + j0] = make_uint2(lo, hi);
    }
}

// ---------------------------------------------------------------------------
// GCN layer phase. Phase-1 i8 GEMM M=64,N=128,K=2048 (LDS As/Bs swizzled).
// Phase-2 (MODE=0): bf16 MFMA, W fragments direct from global (L2-hot).
// MODE=1: h3 + pool.  LDS: As 4K | Bs 8K | Hs 17408 | pmax 1K = 30720.
// ---------------------------------------------------------------------------
template<int PER_N, int MODE>
__device__ void layer_phase(const MegaArgs& a, int vbid, int t,
                            const i8* __restrict__ Yq,
                            const float* __restrict__ bias,
                            const int* __restrict__ absmIn,
                            const u16* __restrict__ WTg,
                            u16* __restrict__ Yout, int* __restrict__ absmBase,
                            char* smem){
    int b = vbid & 15, i0 = (vbid >> 4) * 64;
    const i8* Ab = a.ATi8 + (size_t)b * N_ * N_ + (size_t)i0 * N_;
    const i8* Bb = Yq + (size_t)b * H_ * N_;
    i8*  As = (i8*)smem;
    i8*  Bs = (i8*)(smem + 4096);
    u16* Hs = (u16*)(smem + 12288);            // 64*136*2 = 17408
    float* pmax = (float*)(smem + 29696);
    int w = t >> 6, lane = t & 63, quad = lane >> 4, l16 = lane & 15;
    int mr = w & 1, nc = w >> 1;

    float inv_s = PER_N ? 0.f : __int_as_float(absmIn[b]) * (1.f / 126.f);
    const float* invN = PER_N ? (a.invs1 + b * H_) : nullptr;

    v4i acc[2][4];
    #pragma unroll
    for (int mt = 0; mt < 2; ++mt)
        #pragma unroll
        for (int nt = 0; nt < 4; ++nt) acc[mt][nt] = (v4i){0, 0, 0, 0};

    int srow = lane & 15;
    int sslot = ((lane >> 4) ^ (lane & 3)) * 16;
    int fxo = (quad ^ (l16 & 3)) * 256 + l16 * 16;

    for (int k0 = 0; k0 < N_; k0 += 64){
        #pragma unroll
        for (int it = 0; it < 3; ++it){
            int g = w * 3 + it;
            if (g < 4)
                gld16b(Ab + (size_t)(g * 16 + srow) * N_ + k0 + sslot, As + g * 1024);
            else
                gld16b(Bb + (size_t)((g - 4) * 16 + srow) * N_ + k0 + sslot, Bs + (g - 4) * 1024);
        }
        __syncthreads();
        v4i af[2];
        #pragma unroll
        for (int mt = 0; mt < 2; ++mt)
            af[mt] = *(const v4i*)&As[(mr * 2 + mt) * 1024 + fxo];
        #pragma unroll
        for (int nt = 0; nt < 4; ++nt){
            v4i bv = *(const v4i*)&Bs[(nc * 4 + nt) * 1024 + fxo];
            #pragma unroll
            for (int mt = 0; mt < 2; ++mt)
                acc[mt][nt] = __builtin_amdgcn_mfma_i32_16x16x64_i8(af[mt], bv, acc[mt][nt], 0, 0, 0);
        }
        __syncthreads();
    }

    // epilogue 1: h = relu(dis_i * dequant(acc) + bias) -> Hs
    #pragma unroll
    for (int mt = 0; mt < 2; ++mt)
        #pragma unroll
        for (int r = 0; r < 4; ++r){
            int m = mr * 32 + mt * 16 + quad * 4 + r;
            float dsc = rsqrtf(a.degF[b * N_ + i0 + m]);
            #pragma unroll
            for (int nt = 0; nt < 4; ++nt){
                int n = nc * 64 + nt * 16 + l16;
                float z = (float)acc[mt][nt][r] * (PER_N ? invN[n] : inv_s);
                float v = dsc * z + bias[n];
                Hs[m * 136 + n] = f2bf(v > 0.f ? v : 0.f);
            }
        }
    __syncthreads();

    if (MODE == 0){
        // phase 2: Z2[m,h'] = sum_k Hs[m,k] * WT[h',k]; W frags direct global
        f32x4 a2[2][4];
        #pragma unroll
        for (int mt = 0; mt < 2; ++mt)
            #pragma unroll
            for (int nt = 0; nt < 4; ++nt) a2[mt][nt] = (f32x4){0.f, 0.f, 0.f, 0.f};
        #pragma unroll
        for (int kc = 0; kc < 4; ++kc){
            bf16x8 af[2];
            #pragma unroll
            for (int mt = 0; mt < 2; ++mt)
                af[mt] = *(const bf16x8*)&Hs[(mr * 32 + mt * 16 + l16) * 136 + kc * 32 + quad * 8];
            #pragma unroll
            for (int nt = 0; nt < 4; ++nt){
                bf16x8 bv = *(const bf16x8*)&WTg[(size_t)(nc * 64 + nt * 16 + l16) * H_ + kc * 32 + quad * 8];
                #pragma unroll
                for (int mt = 0; mt < 2; ++mt)
                    a2[mt][nt] = __builtin_amdgcn_mfma_f32_16x16x32_bf16(af[mt], bv, a2[mt][nt], 0, 0, 0);
            }
        }
        __syncthreads();
        float lmax = 0.f;
        #pragma unroll
        for (int mt = 0; mt < 2; ++mt)
            #pragma unroll
            for (int r = 0; r < 4; ++r){
                int m = mr * 32 + mt * 16 + quad * 4 + r;
                float dsc = rsqrtf(a.degF[b * N_ + i0 + m]);
                #pragma unroll
                for (int nt = 0; nt < 4; ++nt){
                    float v = dsc * a2[mt][nt][r];
                    lmax = fmaxf(lmax, fabsf(v));
                    Hs[m * 136 + nc * 64 + nt * 16 + l16] = f2bf(v);
                }
            }
        pmax[t] = lmax;
        __syncthreads();
        size_t obase = (size_t)b * H_ * N_ + i0;
        int j = t & 63, hq = t >> 6;
        #pragma unroll 8
        for (int rep = 0; rep < 32; ++rep){
            int hrow = hq * 32 + rep;
            Yout[obase + (size_t)hrow * N_ + j] = Hs[j * 136 + hrow];
        }
        if (t < 64){
            float mv = fmaxf(fmaxf(pmax[t], pmax[t + 64]), fmaxf(pmax[t + 128], pmax[t + 192]));
            mv = wredM(mv);
            if (t == 0) atomicMax(absmBase + b, __float_as_int(mv));
        }
    } else {
        #pragma unroll
        for (int rep = 0; rep < 4; ++rep){
            int e = rep * 256 + t;
            int row = e >> 4, c8 = e & 15;
            *(uint4*)&a.hbuf[((size_t)b * N_ + i0 + row) * H_ + c8 * 8] = *(const uint4*)&Hs[row * 136 + c8 * 8];
        }
        int n = t & 127, rq = t >> 7;
        float ps = 0.f;
        #pragma unroll 8
        for (int r = 0; r < 32; ++r) ps += bf2f(Hs[(rq * 32 + r) * 136 + n]);
        pmax[t] = ps;
        __syncthreads();
        if (t < 128)
            atomicAdd(&a.poolF[b * H_ + t], (pmax[t] + pmax[t + 128]) * (1.f / N_));
    }
}

__global__ __launch_bounds__(256, 2) void f_l1(MegaArgs a){
    __shared__ __align__(16) char sm[30720];
    layer_phase<1, 0>(a, blockIdx.x, threadIdx.x, a.Yq1, a.b1, nullptr, a.WT2, a.Yb16, a.absm, sm);
}
__global__ __launch_bounds__(256, 2) void f_l2(MegaArgs a){
    __shared__ __align__(16) char sm[30720];
    layer_phase<0, 0>(a, blockIdx.x, threadIdx.x, a.Yq2, a.b2, a.absm, a.WT3, a.Yb16, a.absm + 16, sm);
}
__global__ __launch_bounds__(256, 2) void f_l3(MegaArgs a){
    __shared__ __align__(16) char sm[30720];
    layer_phase<0, 1>(a, blockIdx.x, threadIdx.x, a.Yq1, a.b3, a.absm + 16, nullptr, nullptr, nullptr, sm);
}

// quantize Yb16 -> Yq; stage 0: absm[0..15]->Yq2, stage 1: absm[16..31]->Yq1
template<int S>
__global__ __launch_bounds__(256) void f_q(MegaArgs a){
    const int* am = a.absm + S * 16;
    i8* dst = S ? a.Yq1 : a.Yq2;
    int idx = blockIdx.x * 256 + threadIdx.x;
    #pragma unroll
    for (int it = 0; it < 4; ++it){
        int pos = (it * 131072 + idx) * 8;
        int b = pos >> 18;
        float m = __int_as_float(am[b]);
        float s = (m > 0.f) ? 126.f / m : 0.f;
        bf16x8 y = *(const bf16x8*)&a.Yb16[pos];
        int q[8];
        #pragma unroll
        for (int e = 0; e < 8; ++e) q[e] = (int)rintf(bf2f((u16)y[e]) * s);
        unsigned lo = (q[0] & 255) | ((q[1] & 255) << 8) | ((q[2] & 255) << 16) | ((unsigned)(q[3] & 255) << 24);
        unsigned hi = (q[4] & 255) | ((q[5] & 255) << 8) | ((q[6] & 255) << 16) | ((unsigned)(q[7] & 255) << 24);
        *(uint2*)&dst[pos] = make_uint2(lo, hi);
    }
}

// ---------------------------------------------------------------------------
// Actor MLP + per-block cvec recompute + value head (blocks < 16).
// 64-row wave-local tiles; B operands direct from global (L2-hot).
// ---------------------------------------------------------------------------
__global__ __launch_bounds__(256) void f_actor(MegaArgs a){
    __shared__ __align__(16) u16 M1[64 * 136];
    __shared__ float pl[128], msl[128], cvL[128], v1[32];
    int vbid = blockIdx.x, t = threadIdx.x;
    int b = vbid & 15, i0 = (vbid >> 4) * 64;
    const u16* Ab = a.hbuf + ((size_t)b * N_ + i0) * H_;
    int w = t >> 6, lane = t & 63, quad = lane >> 4, l16 = lane & 15;

    // cvec[b] recomputed per block (A1 cols L2-hot; 32K MACs)
    if (t < 128){ pl[t] = a.poolF[b * H_ + t]; msl[t] = a.ms[t]; }
    __syncthreads();
    if (t < 128){
        float c = a.ab1[t];
        for (int k = 0; k < 128; ++k)
            c += pl[k] * a.A1[(128 + k) * H_ + t] + msl[k] * a.A1[(256 + k) * H_ + t];
        cvL[t] = c;
    } else if (t < 160 && vbid < 16){
        int cc = t - 128;
        float v = a.cb1[cc];
        for (int k = 0; k < 128; ++k) v += pl[k] * a.C1[k * CH_ + cc];
        v1[cc] = v > 0.f ? v : 0.f;
    }
    __syncthreads();
    if (vbid < 16 && t == 0){
        float v = a.cb2[0];
        for (int c = 0; c < CH_; ++c) v += v1[c] * a.C2[c];
        a.out[48 + b] = v;
    }

    f32x4 acc[8];
    #pragma unroll
    for (int nt = 0; nt < 8; ++nt) acc[nt] = (f32x4){0.f, 0.f, 0.f, 0.f};
    // GEMM1: h3 @ A1a (A and B frags direct from global)
    #pragma unroll
    for (int kc = 0; kc < 4; ++kc){
        bf16x8 af = *(const bf16x8*)&Ab[(size_t)(w * 16 + l16) * H_ + kc * 32 + quad * 8];
        #pragma unroll
        for (int nt = 0; nt < 8; ++nt){
            bf16x8 bv = *(const bf16x8*)&a.A1aT[(size_t)(nt * 16 + l16) * H_ + kc * 32 + quad * 8];
            acc[nt] = __builtin_amdgcn_mfma_f32_16x16x32_bf16(af, bv, acc[nt], 0, 0, 0);
        }
    }
    #pragma unroll
    for (int r = 0; r < 4; ++r){
        int m = w * 16 + quad * 4 + r;
        #pragma unroll
        for (int nt = 0; nt < 8; ++nt){
            int n = nt * 16 + l16;
            float v = acc[nt][r] + cvL[n];
            M1[m * 136 + n] = f2bf(v > 0.f ? v : 0.f);
            acc[nt][r] = 0.f;
        }
    }
    // GEMM2: a1 @ A2 (A frag from M1 — wave-local rows; B direct global)
    #pragma unroll
    for (int kc = 0; kc < 4; ++kc){
        bf16x8 af = *(const bf16x8*)&M1[(w * 16 + l16) * 136 + kc * 32 + quad * 8];
        #pragma unroll
        for (int nt = 0; nt < 8; ++nt){
            bf16x8 bv = *(const bf16x8*)&a.A2T[(size_t)(nt * 16 + l16) * H_ + kc * 32 + quad * 8];
            acc[nt] = __builtin_amdgcn_mfma_f32_16x16x32_bf16(af, bv, acc[nt], 0, 0, 0);
        }
    }
    float ab3v = a.ab3[0];
    #pragma unroll
    for (int r = 0; r < 4; ++r){
        int m = w * 16 + quad * 4 + r;
        float part = 0.f;
        #pragma unroll
        for (int nt = 0; nt < 8; ++nt){
            int n = nt * 16 + l16;
            float v = acc[nt][r] + a.ab2[n];
            v = v > 0.f ? v : 0.f;
            part += v * a.A3[n];
        }
        #pragma unroll
        for (int o = 1; o < 16; o <<= 1) part += __shfl_xor(part, o, 64);
        if (l16 == 0) a.scr[(size_t)b * N_ + i0 + m] = (part + ab3v) * 10.f;
    }
}

// ---------------------------------------------------------------------------
// softmax / masked log_softmax / entropy (16 blocks)
// ---------------------------------------------------------------------------
__global__ __launch_bounds__(256) void f_sm(MegaArgs a){
    __shared__ float sc[N_];
    __shared__ float red[4];
    __shared__ float lps;
    int b = blockIdx.x, t = threadIdx.x;
    const float* sp = a.scr + (size_t)b * N_;
    const int*   cp = a.cand + (size_t)b * N_;
    float mx = -1e30f;
    for (int i = t; i < N_; i += 256){ float v = sp[i]; sc[i] = v; mx = fmaxf(mx, v); }
    mx = wredM(mx);
    if ((t & 63) == 0) red[t >> 6] = mx;
    __syncthreads();
    mx = fmaxf(fmaxf(red[0], red[1]), fmaxf(red[2], red[3]));
    __syncthreads();
    float se = 0.f;
    for (int i = t; i < N_; i += 256) se += expf(sc[i] - mx);
    se = wredS(se);
    if ((t & 63) == 0) red[t >> 6] = se;
    __syncthreads();
    float s1 = red[0] + red[1] + red[2] + red[3];
    __syncthreads();
    float inv = 1.f / s1;
    float m2 = -1e30f;
    for (int i = t; i < N_; i += 256){
        float p = expf(sc[i] - mx) * inv;
        sc[i] = p;
        if (cp[i] != 0) m2 = fmaxf(m2, p);
    }
    m2 = wredM(m2);
    if ((t & 63) == 0) red[t >> 6] = m2;
    __syncthreads();
    m2 = fmaxf(fmaxf(red[0], red[1]), fmaxf(red[2], red[3]));
    __syncthreads();
    float s2 = 0.f;
    for (int i = t; i < N_; i += 256) if (cp[i] != 0) s2 += expf(sc[i] - m2);
    s2 = wredS(s2);
    if ((t & 63) == 0) red[t >> 6] = s2;
    __syncthreads();
    float lse = m2 + logf(red[0] + red[1] + red[2] + red[3]);
    __syncthreads();
    int ac = a.act[b];
    float ent = 0.f;
    for (int i = t; i < N_; i += 256){
        float lp = (cp[i] != 0 ? sc[i] : NEG_) - lse;
        float pe = expf(lp);
        ent -= pe * lp;
        if (i == ac) lps = lp;
    }
    ent = wredS(ent);
    if ((t & 63) == 0) red[t >> 6] = ent;
    __syncthreads();
    if (t == 0){
        a.out[b]      = (float)ac;
        a.out[16 + b] = lps;
        a.out[32 + b] = red[0] + red[1] + red[2] + red[3];
    }
}

// ---------------------------------------------------------------------------
extern "C" void kernel_launch(void* const* d_in, const int* in_sizes, int n_in,
                              void* d_out, int out_size, void* d_ws, size_t ws_size,
                              hipStream_t stream) {
    const float* feat = (const float*)d_in[0];
    const int*   adj  = (const int*)d_in[1];

    char* w8 = (char*)d_ws;
    size_t off = 0;
    auto alloc = [&](size_t bytes){ void* p = w8 + off; off += (bytes + 255) & ~(size_t)255; return p; };
    i8*    ATi8  = (i8*)   alloc((size_t)B_ * N_ * N_);
    u16*   Yb16  = (u16*)  alloc((size_t)B_ * H_ * N_ * 2);
    i8*    Yq1   = (i8*)   alloc((size_t)B_ * H_ * N_);
    i8*    Yq2   = (i8*)   alloc((size_t)B_ * H_ * N_);
    u16*   hbuf  = (u16*)  alloc((size_t)B_ * N_ * H_ * 2);
    float* degF  = (float*)alloc((size_t)B_ * N_ * 4);      // zeroed
    float* poolF = (float*)alloc((size_t)B_ * H_ * 4);      // zeroed
    int*   absm  = (int*)  alloc(256);                      // zeroed
    float* m01   = (float*)alloc(32 * 4);
    float* invs1 = (float*)alloc((size_t)B_ * H_ * 4);
    float* scr   = (float*)alloc((size_t)B_ * N_ * 4);
    u16*   WT2   = (u16*)  alloc((size_t)H_ * H_ * 2);
    u16*   WT3   = (u16*)  alloc((size_t)H_ * H_ * 2);
    u16*   A1aT  = (u16*)  alloc((size_t)H_ * H_ * 2);
    u16*   A2T   = (u16*)  alloc((size_t)H_ * H_ * 2);

    hipMemsetAsync(degF, 0, (size_t)B_ * N_ * 4 + (size_t)B_ * H_ * 4 + 256, stream);

    k_prep<<<dim3(32, 32, 16), 256, 0, stream>>>(adj, ATi8, degF);

    MegaArgs ma;
    ma.feat = feat; ma.cand = (const int*)d_in[2]; ma.act = (const int*)d_in[3];
    ma.W1 = (const float*)d_in[4];  ma.b1 = (const float*)d_in[5];
    ma.W2 = (const float*)d_in[6];  ma.b2 = (const float*)d_in[7];
    ma.W3 = (const float*)d_in[8];  ma.b3 = (const float*)d_in[9];
    ma.ms = (const float*)d_in[10];
    ma.A1 = (const float*)d_in[11]; ma.ab1 = (const float*)d_in[12];
    ma.A2 = (const float*)d_in[13]; ma.ab2 = (const float*)d_in[14];
    ma.A3 = (const float*)d_in[15]; ma.ab3 = (const float*)d_in[16];
    ma.C1 = (const float*)d_in[17]; ma.cb1 = (const float*)d_in[18];
    ma.C2 = (const float*)d_in[19]; ma.cb2 = (const float*)d_in[20];
    ma.ATi8 = ATi8; ma.degF = degF; ma.poolF = poolF; ma.absm = absm;
    ma.m01 = m01; ma.invs1 = invs1; ma.scr = scr;
    ma.Yb16 = Yb16; ma.hbuf = hbuf; ma.WT2 = WT2; ma.WT3 = WT3;
    ma.A1aT = A1aT; ma.A2T = A2T; ma.Yq1 = Yq1; ma.Yq2 = Yq2;
    ma.out = (float*)d_out;

    f_p1   <<<dim3(272), 256, 0, stream>>>(ma);
    f_y1q  <<<dim3(512), 256, 0, stream>>>(ma);
    f_l1   <<<dim3(512), 256, 0, stream>>>(ma);
    f_q<0> <<<dim3(512), 256, 0, stream>>>(ma);
    f_l2   <<<dim3(512), 256, 0, stream>>>(ma);
    f_q<1> <<<dim3(512), 256, 0, stream>>>(ma);
    f_l3   <<<dim3(512), 256, 0, stream>>>(ma);
    f_actor<<<dim3(512), 256, 0, stream>>>(ma);
    f_sm   <<<dim3(16),  256, 0, stream>>>(ma);
}

// Round 8
// 543.615 us; speedup vs baseline: 1.9047x; 1.0112x over previous
//
#include <hip/hip_runtime.h>
#include <hip/hip_bf16.h>
#include <stdint.h>

#define B_  16
#define N_  2048
#define D_  2
#define H_  128
#define CH_ 32
#define NEG_ (-1e9f)

typedef __attribute__((ext_vector_type(8))) short bf16x8;
typedef __attribute__((ext_vector_type(4))) float f32x4;
typedef __attribute__((ext_vector_type(4))) int   v4i;
typedef unsigned short u16;
typedef signed char    i8;

__device__ inline u16 f2bf(float f){
    union { __hip_bfloat16 h; u16 u; } cv;
    cv.h = __float2bfloat16(f);
    return cv.u;
}
__device__ inline float bf2f(u16 v){ return __uint_as_float(((unsigned)v) << 16); }

__device__ inline void gld16b(const void* g, void* l){
    __builtin_amdgcn_global_load_lds(
        (const __attribute__((address_space(1))) unsigned int*)g,
        (__attribute__((address_space(3))) unsigned int*)l, 16, 0, 0);
}

__device__ inline float wredS(float v){
    #pragma unroll
    for (int o = 32; o; o >>= 1) v += __shfl_xor(v, o, 64);
    return v;
}
__device__ inline float wredM(float v){
    #pragma unroll
    for (int o = 32; o; o >>= 1) v = fmaxf(v, __shfl_xor(v, o, 64));
    return v;
}

// ---------------------------------------------------------------------------
// K0: adj transpose (int -> i8 {0,1} + self-loops) + column-degree sums.
// ---------------------------------------------------------------------------
__global__ __launch_bounds__(256) void k_prep(const int* __restrict__ adj,
                                              i8* __restrict__ ATi8,
                                              float* __restrict__ degF){
    int i0 = blockIdx.x * 64, j0 = blockIdx.y * 64, b = blockIdx.z;
    __shared__ i8 tile[64 * 80];
    __shared__ float degP[256];
    int t = threadIdx.x;
    const int* ap = adj + (size_t)b * N_ * N_;
    #pragma unroll
    for (int it = 0; it < 4; ++it){
        int jj = it * 16 + (t >> 4);
        int gi0 = (t & 15) * 4;
        int4 a4 = *(const int4*)&ap[(size_t)(j0 + jj) * N_ + i0 + gi0];
        int gj = j0 + jj;
        tile[(gi0 + 0) * 80 + jj] = (a4.x != 0 || gj == i0 + gi0 + 0) ? 1 : 0;
        tile[(gi0 + 1) * 80 + jj] = (a4.y != 0 || gj == i0 + gi0 + 1) ? 1 : 0;
        tile[(gi0 + 2) * 80 + jj] = (a4.z != 0 || gj == i0 + gi0 + 2) ? 1 : 0;
        tile[(gi0 + 3) * 80 + jj] = (a4.w != 0 || gj == i0 + gi0 + 3) ? 1 : 0;
    }
    __syncthreads();
    {
        int ii = t & 63, q = t >> 6;
        float s = 0.f;
        #pragma unroll
        for (int k = 0; k < 16; ++k) s += (float)tile[ii * 80 + q * 16 + k];
        degP[t] = s;
    }
    __syncthreads();
    if (t < 64){
        float s = degP[t] + degP[t + 64] + degP[t + 128] + degP[t + 192];
        atomicAdd(&degF[b * N_ + i0 + t], s);
    }
    i8* op = ATi8 + (size_t)b * N_ * N_;
    {
        int io = t >> 2, slot = (t & 3) * 16;
        *(uint4*)&op[(size_t)(i0 + io) * N_ + j0 + slot] = *(const uint4*)&tile[io * 80 + slot];
    }
}

// ---------------------------------------------------------------------------
struct MegaArgs {
    const float *feat; const int *cand; const int *act;
    const float *W1, *b1, *W2, *b2, *W3, *b3, *ms;
    const float *A1, *ab1, *A2, *ab2, *A3, *ab3;
    const float *C1, *cb1, *C2, *cb2;
    const i8 *ATi8;
    float *degF, *poolF; int *absm;     // absm[0..15] stage2, [16..31] stage3
    float *invs1, *scr;
    u16 *Yb16, *hbuf, *WT2, *WT3, *A1aT, *A2T;
    i8 *Yq1, *Yq2;
    float *out;
};

// ---------------------------------------------------------------------------
// P2: Y1 quantized directly (analytic per-h bound, per-block featmax recompute)
//     + folded weight transposes (4 x 128x128, 128 elements per block).
// ---------------------------------------------------------------------------
__global__ __launch_bounds__(256) void f_y1q(MegaArgs a){
    __shared__ float r0[256], r1[256];
    __shared__ float m01[2];
    int vb = blockIdx.x, t = threadIdx.x;
    int b = vb & 15, seg = vb >> 4;       // seg 0..31 -> 4 h rows

    // folded transposes: element e = vb*128 + (t-128), matrices in 16384 chunks
    if (t >= 128){
        int e = vb * 128 + (t - 128);
        int q = e >> 14, idx = e & 16383;
        const float* s; u16* d;
        switch (q){
            case 0: s = a.W2; d = a.WT2; break;
            case 1: s = a.W3; d = a.WT3; break;
            case 2: s = a.A1; d = a.A1aT; break;
            default: s = a.A2; d = a.A2T; break;
        }
        int hp = idx >> 7, k = idx & 127;
        d[hp * 128 + k] = f2bf(s[k * 128 + hp]);
    }

    // load feat slice + deg for own 8 j's
    int j0 = t * 8;
    float4 f4[4];
    #pragma unroll
    for (int k = 0; k < 4; ++k)
        f4[k] = *(const float4*)&a.feat[((size_t)b * N_ + j0) * 2 + k * 4];
    const float* ff = (const float*)f4;
    float dsj[8];
    #pragma unroll
    for (int e = 0; e < 8; ++e) dsj[e] = rsqrtf(a.degF[b * N_ + j0 + e]);

    // per-block featmax (identical across the 32 blocks of batch b)
    float lm0 = 0.f, lm1 = 0.f;
    #pragma unroll
    for (int e = 0; e < 8; ++e){
        lm0 = fmaxf(lm0, dsj[e] * fabsf(ff[2 * e]));
        lm1 = fmaxf(lm1, dsj[e] * fabsf(ff[2 * e + 1]));
    }
    r0[t] = lm0; r1[t] = lm1;
    __syncthreads();
    if (t < 128){ r0[t] = fmaxf(r0[t], r0[t + 128]); r1[t] = fmaxf(r1[t], r1[t + 128]); }
    __syncthreads();
    if (t < 64){
        float m0 = wredM(fmaxf(r0[t], r0[t + 64]));
        float m1 = wredM(fmaxf(r1[t], r1[t + 64]));
        if (t == 0){ m01[0] = m0; m01[1] = m1; }
    }
    __syncthreads();
    float m0 = m01[0], m1 = m01[1];

    #pragma unroll
    for (int hh = 0; hh < 4; ++hh){
        int h = seg * 4 + hh;
        float w0 = a.W1[h], w1 = a.W1[H_ + h];
        float bound = m0 * fabsf(w0) + m1 * fabsf(w1);
        float s = (bound > 0.f) ? 126.f / bound : 0.f;
        if (t == 0) a.invs1[b * H_ + h] = bound * (1.f / 126.f);
        int q[8];
        #pragma unroll
        for (int e = 0; e < 8; ++e){
            float v = dsj[e] * (ff[2 * e] * w0 + ff[2 * e + 1] * w1);
            q[e] = (int)rintf(v * s);
        }
        unsigned lo = (q[0] & 255) | ((q[1] & 255) << 8) | ((q[2] & 255) << 16) | ((unsigned)(q[3] & 255) << 24);
        unsigned hi = (q[4] & 255) | ((q[5] & 255) << 8) | ((q[6] & 255) << 16) | ((unsigned)(q[7] & 255) << 24);
        *(uint2*)&a.Yq1[(size_t)b * H_ * N_ + (size_t)h * N_ + j0] = make_uint2(lo, hi);
    }
}

// ---------------------------------------------------------------------------
// GCN layer phase. Phase-1 i8 GEMM M=64,N=128,K=2048 (LDS As/Bs swizzled).
// Phase-2 (MODE=0): bf16 MFMA, W fragments direct from global (L2-hot).
// MODE=1: h3 + pool.  LDS: As 4K | Bs 8K | Hs 17408 | pmax 1K = 30720.
// ---------------------------------------------------------------------------
template<int PER_N, int MODE>
__device__ void layer_phase(const MegaArgs& a, int vbid, int t,
                            const i8* __restrict__ Yq,
                            const float* __restrict__ bias,
                            const int* __restrict__ absmIn,
                            const u16* __restrict__ WTg,
                            u16* __restrict__ Yout, int* __restrict__ absmBase,
                            char* smem){
    int b = vbid & 15, i0 = (vbid >> 4) * 64;
    const i8* Ab = a.ATi8 + (size_t)b * N_ * N_ + (size_t)i0 * N_;
    const i8* Bb = Yq + (size_t)b * H_ * N_;
    i8*  As = (i8*)smem;
    i8*  Bs = (i8*)(smem + 4096);
    u16* Hs = (u16*)(smem + 12288);            // 64*136*2 = 17408
    float* pmax = (float*)(smem + 29696);
    int w = t >> 6, lane = t & 63, quad = lane >> 4, l16 = lane & 15;
    int mr = w & 1, nc = w >> 1;

    float inv_s = PER_N ? 0.f : __int_as_float(absmIn[b]) * (1.f / 126.f);
    const float* invN = PER_N ? (a.invs1 + b * H_) : nullptr;

    v4i acc[2][4];
    #pragma unroll
    for (int mt = 0; mt < 2; ++mt)
        #pragma unroll
        for (int nt = 0; nt < 4; ++nt) acc[mt][nt] = (v4i){0, 0, 0, 0};

    int srow = lane & 15;
    int sslot = ((lane >> 4) ^ (lane & 3)) * 16;
    int fxo = (quad ^ (l16 & 3)) * 256 + l16 * 16;

    for (int k0 = 0; k0 < N_; k0 += 64){
        #pragma unroll
        for (int it = 0; it < 3; ++it){
            int g = w * 3 + it;
            if (g < 4)
                gld16b(Ab + (size_t)(g * 16 + srow) * N_ + k0 + sslot, As + g * 1024);
            else
                gld16b(Bb + (size_t)((g - 4) * 16 + srow) * N_ + k0 + sslot, Bs + (g - 4) * 1024);
        }
        __syncthreads();
        v4i af[2];
        #pragma unroll
        for (int mt = 0; mt < 2; ++mt)
            af[mt] = *(const v4i*)&As[(mr * 2 + mt) * 1024 + fxo];
        #pragma unroll
        for (int nt = 0; nt < 4; ++nt){
            v4i bv = *(const v4i*)&Bs[(nc * 4 + nt) * 1024 + fxo];
            #pragma unroll
            for (int mt = 0; mt < 2; ++mt)
                acc[mt][nt] = __builtin_amdgcn_mfma_i32_16x16x64_i8(af[mt], bv, acc[mt][nt], 0, 0, 0);
        }
        __syncthreads();
    }

    // epilogue 1: h = relu(dis_i * dequant(acc) + bias) -> Hs
    #pragma unroll
    for (int mt = 0; mt < 2; ++mt)
        #pragma unroll
        for (int r = 0; r < 4; ++r){
            int m = mr * 32 + mt * 16 + quad * 4 + r;
            float dsc = rsqrtf(a.degF[b * N_ + i0 + m]);
            #pragma unroll
            for (int nt = 0; nt < 4; ++nt){
                int n = nc * 64 + nt * 16 + l16;
                float z = (float)acc[mt][nt][r] * (PER_N ? invN[n] : inv_s);
                float v = dsc * z + bias[n];
                Hs[m * 136 + n] = f2bf(v > 0.f ? v : 0.f);
            }
        }
    __syncthreads();

    if (MODE == 0){
        // phase 2: Z2[m,h'] = sum_k Hs[m,k] * WT[h',k]; W frags direct global
        f32x4 a2[2][4];
        #pragma unroll
        for (int mt = 0; mt < 2; ++mt)
            #pragma unroll
            for (int nt = 0; nt < 4; ++nt) a2[mt][nt] = (f32x4){0.f, 0.f, 0.f, 0.f};
        #pragma unroll
        for (int kc = 0; kc < 4; ++kc){
            bf16x8 af[2];
            #pragma unroll
            for (int mt = 0; mt < 2; ++mt)
                af[mt] = *(const bf16x8*)&Hs[(mr * 32 + mt * 16 + l16) * 136 + kc * 32 + quad * 8];
            #pragma unroll
            for (int nt = 0; nt < 4; ++nt){
                bf16x8 bv = *(const bf16x8*)&WTg[(size_t)(nc * 64 + nt * 16 + l16) * H_ + kc * 32 + quad * 8];
                #pragma unroll
                for (int mt = 0; mt < 2; ++mt)
                    a2[mt][nt] = __builtin_amdgcn_mfma_f32_16x16x32_bf16(af[mt], bv, a2[mt][nt], 0, 0, 0);
            }
        }
        __syncthreads();
        float lmax = 0.f;
        #pragma unroll
        for (int mt = 0; mt < 2; ++mt)
            #pragma unroll
            for (int r = 0; r < 4; ++r){
                int m = mr * 32 + mt * 16 + quad * 4 + r;
                float dsc = rsqrtf(a.degF[b * N_ + i0 + m]);
                #pragma unroll
                for (int nt = 0; nt < 4; ++nt){
                    float v = dsc * a2[mt][nt][r];
                    lmax = fmaxf(lmax, fabsf(v));
                    Hs[m * 136 + nc * 64 + nt * 16 + l16] = f2bf(v);
                }
            }
        pmax[t] = lmax;
        __syncthreads();
        size_t obase = (size_t)b * H_ * N_ + i0;
        int j = t & 63, hq = t >> 6;
        #pragma unroll 8
        for (int rep = 0; rep < 32; ++rep){
            int hrow = hq * 32 + rep;
            Yout[obase + (size_t)hrow * N_ + j] = Hs[j * 136 + hrow];
        }
        if (t < 64){
            float mv = fmaxf(fmaxf(pmax[t], pmax[t + 64]), fmaxf(pmax[t + 128], pmax[t + 192]));
            mv = wredM(mv);
            if (t == 0) atomicMax(absmBase + b, __float_as_int(mv));
        }
    } else {
        #pragma unroll
        for (int rep = 0; rep < 4; ++rep){
            int e = rep * 256 + t;
            int row = e >> 4, c8 = e & 15;
            *(uint4*)&a.hbuf[((size_t)b * N_ + i0 + row) * H_ + c8 * 8] = *(const uint4*)&Hs[row * 136 + c8 * 8];
        }
        int n = t & 127, rq = t >> 7;
        float ps = 0.f;
        #pragma unroll 8
        for (int r = 0; r < 32; ++r) ps += bf2f(Hs[(rq * 32 + r) * 136 + n]);
        pmax[t] = ps;
        __syncthreads();
        if (t < 128)
            atomicAdd(&a.poolF[b * H_ + t], (pmax[t] + pmax[t + 128]) * (1.f / N_));
    }
}

__global__ __launch_bounds__(256, 2) void f_l1(MegaArgs a){
    __shared__ __align__(16) char sm[30720];
    layer_phase<1, 0>(a, blockIdx.x, threadIdx.x, a.Yq1, a.b1, nullptr, a.WT2, a.Yb16, a.absm, sm);
}
__global__ __launch_bounds__(256, 2) void f_l2(MegaArgs a){
    __shared__ __align__(16) char sm[30720];
    layer_phase<0, 0>(a, blockIdx.x, threadIdx.x, a.Yq2, a.b2, a.absm, a.WT3, a.Yb16, a.absm + 16, sm);
}
__global__ __launch_bounds__(256, 2) void f_l3(MegaArgs a){
    __shared__ __align__(16) char sm[30720];
    layer_phase<0, 1>(a, blockIdx.x, threadIdx.x, a.Yq1, a.b3, a.absm + 16, nullptr, nullptr, nullptr, sm);
}

// quantize Yb16 -> Yq; stage 0: absm[0..15]->Yq2, stage 1: absm[16..31]->Yq1
template<int S>
__global__ __launch_bounds__(256) void f_q(MegaArgs a){
    const int* am = a.absm + S * 16;
    i8* dst = S ? a.Yq1 : a.Yq2;
    int idx = blockIdx.x * 256 + threadIdx.x;
    #pragma unroll
    for (int it = 0; it < 4; ++it){
        int pos = (it * 131072 + idx) * 8;
        int b = pos >> 18;
        float m = __int_as_float(am[b]);
        float s = (m > 0.f) ? 126.f / m : 0.f;
        bf16x8 y = *(const bf16x8*)&a.Yb16[pos];
        int q[8];
        #pragma unroll
        for (int e = 0; e < 8; ++e) q[e] = (int)rintf(bf2f((u16)y[e]) * s);
        unsigned lo = (q[0] & 255) | ((q[1] & 255) << 8) | ((q[2] & 255) << 16) | ((unsigned)(q[3] & 255) << 24);
        unsigned hi = (q[4] & 255) | ((q[5] & 255) << 8) | ((q[6] & 255) << 16) | ((unsigned)(q[7] & 255) << 24);
        *(uint2*)&dst[pos] = make_uint2(lo, hi);
    }
}

// ---------------------------------------------------------------------------
// Actor MLP + per-block cvec recompute + value head (blocks < 16).
// ---------------------------------------------------------------------------
__global__ __launch_bounds__(256) void f_actor(MegaArgs a){
    __shared__ __align__(16) u16 M1[64 * 136];
    __shared__ float pl[128], msl[128], cvL[128], v1[32];
    int vbid = blockIdx.x, t = threadIdx.x;
    int b = vbid & 15, i0 = (vbid >> 4) * 64;
    const u16* Ab = a.hbuf + ((size_t)b * N_ + i0) * H_;
    int w = t >> 6, lane = t & 63, quad = lane >> 4, l16 = lane & 15;

    if (t < 128){ pl[t] = a.poolF[b * H_ + t]; msl[t] = a.ms[t]; }
    __syncthreads();
    if (t < 128){
        float c = a.ab1[t];
        for (int k = 0; k < 128; ++k)
            c += pl[k] * a.A1[(128 + k) * H_ + t] + msl[k] * a.A1[(256 + k) * H_ + t];
        cvL[t] = c;
    } else if (t < 160 && vbid < 16){
        int cc = t - 128;
        float v = a.cb1[cc];
        for (int k = 0; k < 128; ++k) v += pl[k] * a.C1[k * CH_ + cc];
        v1[cc] = v > 0.f ? v : 0.f;
    }
    __syncthreads();
    if (vbid < 16 && t == 0){
        float v = a.cb2[0];
        for (int c = 0; c < CH_; ++c) v += v1[c] * a.C2[c];
        a.out[48 + b] = v;
    }

    f32x4 acc[8];
    #pragma unroll
    for (int nt = 0; nt < 8; ++nt) acc[nt] = (f32x4){0.f, 0.f, 0.f, 0.f};
    #pragma unroll
    for (int kc = 0; kc < 4; ++kc){
        bf16x8 af = *(const bf16x8*)&Ab[(size_t)(w * 16 + l16) * H_ + kc * 32 + quad * 8];
        #pragma unroll
        for (int nt = 0; nt < 8; ++nt){
            bf16x8 bv = *(const bf16x8*)&a.A1aT[(size_t)(nt * 16 + l16) * H_ + kc * 32 + quad * 8];
            acc[nt] = __builtin_amdgcn_mfma_f32_16x16x32_bf16(af, bv, acc[nt], 0, 0, 0);
        }
    }
    #pragma unroll
    for (int r = 0; r < 4; ++r){
        int m = w * 16 + quad * 4 + r;
        #pragma unroll
        for (int nt = 0; nt < 8; ++nt){
            int n = nt * 16 + l16;
            float v = acc[nt][r] + cvL[n];
            M1[m * 136 + n] = f2bf(v > 0.f ? v : 0.f);
            acc[nt][r] = 0.f;
        }
    }
    #pragma unroll
    for (int kc = 0; kc < 4; ++kc){
        bf16x8 af = *(const bf16x8*)&M1[(w * 16 + l16) * 136 + kc * 32 + quad * 8];
        #pragma unroll
        for (int nt = 0; nt < 8; ++nt){
            bf16x8 bv = *(const bf16x8*)&a.A2T[(size_t)(nt * 16 + l16) * H_ + kc * 32 + quad * 8];
            acc[nt] = __builtin_amdgcn_mfma_f32_16x16x32_bf16(af, bv, acc[nt], 0, 0, 0);
        }
    }
    float ab3v = a.ab3[0];
    #pragma unroll
    for (int r = 0; r < 4; ++r){
        int m = w * 16 + quad * 4 + r;
        float part = 0.f;
        #pragma unroll
        for (int nt = 0; nt < 8; ++nt){
            int n = nt * 16 + l16;
            float v = acc[nt][r] + a.ab2[n];
            v = v > 0.f ? v : 0.f;
            part += v * a.A3[n];
        }
        #pragma unroll
        for (int o = 1; o < 16; o <<= 1) part += __shfl_xor(part, o, 64);
        if (l16 == 0) a.scr[(size_t)b * N_ + i0 + m] = (part + ab3v) * 10.f;
    }
}

// ---------------------------------------------------------------------------
// softmax / masked log_softmax / entropy (16 blocks)
// ---------------------------------------------------------------------------
__global__ __launch_bounds__(256) void f_sm(MegaArgs a){
    __shared__ float sc[N_];
    __shared__ float red[4];
    __shared__ float lps;
    int b = blockIdx.x, t = threadIdx.x;
    const float* sp = a.scr + (size_t)b * N_;
    const int*   cp = a.cand + (size_t)b * N_;
    float mx = -1e30f;
    for (int i = t; i < N_; i += 256){ float v = sp[i]; sc[i] = v; mx = fmaxf(mx, v); }
    mx = wredM(mx);
    if ((t & 63) == 0) red[t >> 6] = mx;
    __syncthreads();
    mx = fmaxf(fmaxf(red[0], red[1]), fmaxf(red[2], red[3]));
    __syncthreads();
    float se = 0.f;
    for (int i = t; i < N_; i += 256) se += expf(sc[i] - mx);
    se = wredS(se);
    if ((t & 63) == 0) red[t >> 6] = se;
    __syncthreads();
    float s1 = red[0] + red[1] + red[2] + red[3];
    __syncthreads();
    float inv = 1.f / s1;
    float m2 = -1e30f;
    for (int i = t; i < N_; i += 256){
        float p = expf(sc[i] - mx) * inv;
        sc[i] = p;
        if (cp[i] != 0) m2 = fmaxf(m2, p);
    }
    m2 = wredM(m2);
    if ((t & 63) == 0) red[t >> 6] = m2;
    __syncthreads();
    m2 = fmaxf(fmaxf(red[0], red[1]), fmaxf(red[2], red[3]));
    __syncthreads();
    float s2 = 0.f;
    for (int i = t; i < N_; i += 256) if (cp[i] != 0) s2 += expf(sc[i] - m2);
    s2 = wredS(s2);
    if ((t & 63) == 0) red[t >> 6] = s2;
    __syncthreads();
    float lse = m2 + logf(red[0] + red[1] + red[2] + red[3]);
    __syncthreads();
    int ac = a.act[b];
    float ent = 0.f;
    for (int i = t; i < N_; i += 256){
        float lp = (cp[i] != 0 ? sc[i] : NEG_) - lse;
        float pe = expf(lp);
        ent -= pe * lp;
        if (i == ac) lps = lp;
    }
    ent = wredS(ent);
    if ((t & 63) == 0) red[t >> 6] = ent;
    __syncthreads();
    if (t == 0){
        a.out[b]      = (float)ac;
        a.out[16 + b] = lps;
        a.out[32 + b] = red[0] + red[1] + red[2] + red[3];
    }
}

// ---------------------------------------------------------------------------
extern "C" void kernel_launch(void* const* d_in, const int* in_sizes, int n_in,
                              void* d_out, int out_size, void* d_ws, size_t ws_size,
                              hipStream_t stream) {
    const float* feat = (const float*)d_in[0];
    const int*   adj  = (const int*)d_in[1];

    char* w8 = (char*)d_ws;
    size_t off = 0;
    auto alloc = [&](size_t bytes){ void* p = w8 + off; off += (bytes + 255) & ~(size_t)255; return p; };
    i8*    ATi8  = (i8*)   alloc((size_t)B_ * N_ * N_);
    u16*   Yb16  = (u16*)  alloc((size_t)B_ * H_ * N_ * 2);
    i8*    Yq1   = (i8*)   alloc((size_t)B_ * H_ * N_);
    i8*    Yq2   = (i8*)   alloc((size_t)B_ * H_ * N_);
    u16*   hbuf  = (u16*)  alloc((size_t)B_ * N_ * H_ * 2);
    float* degF  = (float*)alloc((size_t)B_ * N_ * 4);      // zeroed
    float* poolF = (float*)alloc((size_t)B_ * H_ * 4);      // zeroed
    int*   absm  = (int*)  alloc(256);                      // zeroed
    float* invs1 = (float*)alloc((size_t)B_ * H_ * 4);
    float* scr   = (float*)alloc((size_t)B_ * N_ * 4);
    u16*   WT2   = (u16*)  alloc((size_t)H_ * H_ * 2);
    u16*   WT3   = (u16*)  alloc((size_t)H_ * H_ * 2);
    u16*   A1aT  = (u16*)  alloc((size_t)H_ * H_ * 2);
    u16*   A2T   = (u16*)  alloc((size_t)H_ * H_ * 2);

    hipMemsetAsync(degF, 0, (size_t)B_ * N_ * 4 + (size_t)B_ * H_ * 4 + 256, stream);

    k_prep<<<dim3(32, 32, 16), 256, 0, stream>>>(adj, ATi8, degF);

    MegaArgs ma;
    ma.feat = feat; ma.cand = (const int*)d_in[2]; ma.act = (const int*)d_in[3];
    ma.W1 = (const float*)d_in[4];  ma.b1 = (const float*)d_in[5];
    ma.W2 = (const float*)d_in[6];  ma.b2 = (const float*)d_in[7];
    ma.W3 = (const float*)d_in[8];  ma.b3 = (const float*)d_in[9];
    ma.ms = (const float*)d_in[10];
    ma.A1 = (const float*)d_in[11]; ma.ab1 = (const float*)d_in[12];
    ma.A2 = (const float*)d_in[13]; ma.ab2 = (const float*)d_in[14];
    ma.A3 = (const float*)d_in[15]; ma.ab3 = (const float*)d_in[16];
    ma.C1 = (const float*)d_in[17]; ma.cb1 = (const float*)d_in[18];
    ma.C2 = (const float*)d_in[19]; ma.cb2 = (const float*)d_in[20];
    ma.ATi8 = ATi8; ma.degF = degF; ma.poolF = poolF; ma.absm = absm;
    ma.invs1 = invs1; ma.scr = scr;
    ma.Yb16 = Yb16; ma.hbuf = hbuf; ma.WT2 = WT2; ma.WT3 = WT3;
    ma.A1aT = A1aT; ma.A2T = A2T; ma.Yq1 = Yq1; ma.Yq2 = Yq2;
    ma.out = (float*)d_out;

    f_y1q  <<<dim3(512), 256, 0, stream>>>(ma);
    f_l1   <<<dim3(512), 256, 0, stream>>>(ma);
    f_q<0> <<<dim3(512), 256, 0, stream>>>(ma);
    f_l2   <<<dim3(512), 256, 0, stream>>>(ma);
    f_q<1> <<<dim3(512), 256, 0, stream>>>(ma);
    f_l3   <<<dim3(512), 256, 0, stream>>>(ma);
    f_actor<<<dim3(512), 256, 0, stream>>>(ma);
    f_sm   <<<dim3(16),  256, 0, stream>>>(ma);
}